// Round 1
// baseline (1096.851 us; speedup 1.0000x reference)
//
#include <hip/hip_runtime.h>

#define BATCH 2048
#define SEQ 128
#define F 512       // INPUT_DIM == DIM == 512
#define NACT 128
#define GN_EPS 1e-5f

typedef float vfloat4 __attribute__((ext_vector_type(4)));

__device__ __forceinline__ float4 ntload4(const float* p) {
    vfloat4 v = __builtin_nontemporal_load(reinterpret_cast<const vfloat4*>(p));
    return make_float4(v.x, v.y, v.z, v.w);
}

// ---------------------------------------------------------------------------
// Kernel 1: masked mean over SEQ + GroupNorm(1,1) per sample, for both tensors.
// grid (BATCH, 2), block 512. float4-coalesced nontemporal streaming reads
// (1 KB/wave/instr); known trip count so the compiler pipelines loads.
// ---------------------------------------------------------------------------
__global__ __launch_bounds__(512) void k_avg_gn(const float* __restrict__ pre,
                                                const float* __restrict__ eff,
                                                const float* __restrict__ gamma,
                                                const float* __restrict__ beta,
                                                float* __restrict__ Np,
                                                float* __restrict__ Ne) {
    const int b = blockIdx.x;
    const int t = blockIdx.y;
    const float* x = (t == 0 ? pre : eff) + (size_t)b * SEQ * F;
    float* dst = (t == 0 ? Np : Ne) + (size_t)b * F;

    __shared__ float psum[4][F];
    __shared__ float pcnt[4][F];
    __shared__ float red[8];
    __shared__ float mv[2];

    const int tid = threadIdx.x;
    const int g = tid >> 7;           // 0..3 : seq-phase group
    const int fb = (tid & 127) << 2;  // 0..508 : feature base (float4)

    float4 s4 = make_float4(0.f, 0.f, 0.f, 0.f);
    float4 c4 = make_float4(0.f, 0.f, 0.f, 0.f);
    const float* xp = x + (size_t)g * F + fb;
    #pragma unroll 8
    for (int it = 0; it < SEQ / 4; ++it) {
        const float4 v = ntload4(xp + (size_t)it * 4 * F);
        s4.x += v.x; s4.y += v.y; s4.z += v.z; s4.w += v.w;
        c4.x += (v.x != 0.f) ? 1.f : 0.f;
        c4.y += (v.y != 0.f) ? 1.f : 0.f;
        c4.z += (v.z != 0.f) ? 1.f : 0.f;
        c4.w += (v.w != 0.f) ? 1.f : 0.f;
    }
    *reinterpret_cast<float4*>(&psum[g][fb]) = s4;
    *reinterpret_cast<float4*>(&pcnt[g][fb]) = c4;
    __syncthreads();

    const int f = tid;  // 0..511, one feature per thread
    float sum = psum[0][f] + psum[1][f] + psum[2][f] + psum[3][f];
    float cnt = pcnt[0][f] + pcnt[1][f] + pcnt[2][f] + pcnt[3][f];
    const float avg = sum / cnt;  // masked mean (cnt==0 -> inf/nan, matches ref)

    const int lane = tid & 63, wv = tid >> 6;

    // mean over the 512 features
    float r = avg;
    #pragma unroll
    for (int off = 32; off; off >>= 1) r += __shfl_down(r, off, 64);
    if (lane == 0) red[wv] = r;
    __syncthreads();
    if (tid == 0) {
        float m = 0.f;
        #pragma unroll
        for (int i = 0; i < 8; ++i) m += red[i];
        mv[0] = m * (1.f / F);
    }
    __syncthreads();
    const float m = mv[0];
    const float d = avg - m;

    // variance (two-pass, matches ref mean((x-m)^2))
    r = d * d;
    #pragma unroll
    for (int off = 32; off; off >>= 1) r += __shfl_down(r, off, 64);
    if (lane == 0) red[wv] = r;
    __syncthreads();
    if (tid == 0) {
        float v = 0.f;
        #pragma unroll
        for (int i = 0; i < 8; ++i) v += red[i];
        mv[1] = v * (1.f / F);
    }
    __syncthreads();
    const float var = mv[1];
    const float inv = 1.f / sqrtf(var + GN_EPS);

    dst[f] = gamma[0] * d * inv + beta[0];
}

// ---------------------------------------------------------------------------
// Kernel 2: counting-sort batches by action (single block). Produces
// sorted batch indices + group start offsets for k_transform.
// ---------------------------------------------------------------------------
__global__ __launch_bounds__(256) void k_sort(const int* __restrict__ action,
                                              int* __restrict__ sorted,
                                              int* __restrict__ gstart) {
    __shared__ int cnt[NACT];
    __shared__ int start[NACT + 1];
    const int tid = threadIdx.x;
    if (tid < NACT) cnt[tid] = 0;
    __syncthreads();
    for (int b = tid; b < BATCH; b += 256) atomicAdd(&cnt[action[b]], 1);
    __syncthreads();
    if (tid == 0) {
        int acc = 0;
        for (int a = 0; a < NACT; ++a) { start[a] = acc; acc += cnt[a]; }
        start[NACT] = acc;
    }
    __syncthreads();
    if (tid <= NACT) gstart[tid] = start[tid];
    if (tid < NACT) cnt[tid] = start[tid];  // running offsets
    __syncthreads();
    for (int b = tid; b < BATCH; b += 256) {
        const int pos = atomicAdd(&cnt[action[b]], 1);
        sorted[pos] = b;
    }
}

// ---------------------------------------------------------------------------
// Kernel 3: embed GEMMs. z=0: Ep = Np @ pw^T + pb (to ws)
//                        z=1: outE = Ne @ ew^T + eb (to d_out second half)
// 64x64 block tile, BK=16, 256 threads, 4x4 micro-tile.
// ---------------------------------------------------------------------------
__global__ __launch_bounds__(256) void k_embed(const float* __restrict__ Np,
                                               const float* __restrict__ Ne,
                                               const float* __restrict__ pw,
                                               const float* __restrict__ pb,
                                               const float* __restrict__ ew,
                                               const float* __restrict__ eb,
                                               float* __restrict__ Ep,
                                               float* __restrict__ outE) {
    const int z = blockIdx.z;
    const float* A = z ? Ne : Np;     // [2048, 512]
    const float* Bw = z ? ew : pw;    // [512, 512], row i is weight row
    const float* bias = z ? eb : pb;  // [512]
    float* D = z ? outE : Ep;         // [2048, 512]

    const int m0 = blockIdx.x * 64;
    const int n0 = blockIdx.y * 64;

    __shared__ float As[16][68];  // As[k][m]
    __shared__ float Bs[16][68];  // Bs[k][n]

    const int tid = threadIdx.x;
    const int lr = tid >> 2;         // 0..63
    const int lk = (tid & 3) << 2;   // 0,4,8,12
    const int tx = tid & 15, ty = tid >> 4;

    float acc[4][4] = {};
    for (int k0 = 0; k0 < F; k0 += 16) {
        const float4 av = *reinterpret_cast<const float4*>(A + (size_t)(m0 + lr) * F + k0 + lk);
        const float4 bv = *reinterpret_cast<const float4*>(Bw + (size_t)(n0 + lr) * F + k0 + lk);
        As[lk + 0][lr] = av.x; As[lk + 1][lr] = av.y; As[lk + 2][lr] = av.z; As[lk + 3][lr] = av.w;
        Bs[lk + 0][lr] = bv.x; Bs[lk + 1][lr] = bv.y; Bs[lk + 2][lr] = bv.z; Bs[lk + 3][lr] = bv.w;
        __syncthreads();
        #pragma unroll
        for (int k = 0; k < 16; ++k) {
            const float4 a = *reinterpret_cast<const float4*>(&As[k][ty * 4]);
            const float4 bq = *reinterpret_cast<const float4*>(&Bs[k][tx * 4]);
            acc[0][0] = fmaf(a.x, bq.x, acc[0][0]); acc[0][1] = fmaf(a.x, bq.y, acc[0][1]);
            acc[0][2] = fmaf(a.x, bq.z, acc[0][2]); acc[0][3] = fmaf(a.x, bq.w, acc[0][3]);
            acc[1][0] = fmaf(a.y, bq.x, acc[1][0]); acc[1][1] = fmaf(a.y, bq.y, acc[1][1]);
            acc[1][2] = fmaf(a.y, bq.z, acc[1][2]); acc[1][3] = fmaf(a.y, bq.w, acc[1][3]);
            acc[2][0] = fmaf(a.z, bq.x, acc[2][0]); acc[2][1] = fmaf(a.z, bq.y, acc[2][1]);
            acc[2][2] = fmaf(a.z, bq.z, acc[2][2]); acc[2][3] = fmaf(a.z, bq.w, acc[2][3]);
            acc[3][0] = fmaf(a.w, bq.x, acc[3][0]); acc[3][1] = fmaf(a.w, bq.y, acc[3][1]);
            acc[3][2] = fmaf(a.w, bq.z, acc[3][2]); acc[3][3] = fmaf(a.w, bq.w, acc[3][3]);
        }
        __syncthreads();
    }

    const float4 b4 = *reinterpret_cast<const float4*>(bias + n0 + tx * 4);
    #pragma unroll
    for (int i = 0; i < 4; ++i) {
        float4 o;
        o.x = acc[i][0] + b4.x;
        o.y = acc[i][1] + b4.y;
        o.z = acc[i][2] + b4.z;
        o.w = acc[i][3] + b4.w;
        *reinterpret_cast<float4*>(D + (size_t)(m0 + ty * 4 + i) * F + n0 + tx * 4) = o;
    }
}

// ---------------------------------------------------------------------------
// Kernel 4 (v2): p_transformed = W[a] @ Ep[b]  as per-action tiled GEMM.
// out[m, i] = sum_j Ep[bbs[m]][j] * W[a][i][j]   (same math shape as k_embed)
// grid (NACT, 8): block = (action a, 64-col tile). 256 threads = 4 waves.
// M-tile = 32 group batches (dummy-padded; covers ~all groups, mean 16, sd 4),
// N-tile = 64, BK = 16, 4x2 micro-tile. No cross-lane ops; W read exactly once.
// ---------------------------------------------------------------------------
__global__ __launch_bounds__(256) void k_transform(const float* __restrict__ W,
                                                   const float* __restrict__ Ep,
                                                   const int* __restrict__ sorted,
                                                   const int* __restrict__ gstart,
                                                   float* __restrict__ outP) {
    const int a = blockIdx.x;
    const int s0 = gstart[a], s1 = gstart[a + 1];
    if (s0 == s1) return;
    const int n0 = blockIdx.y * 64;
    const float* Wa = W + (size_t)a * F * F;

    __shared__ float As[16][36];   // As[k][m], m = 0..31 (+pad)
    __shared__ float Bs[16][68];   // Bs[k][n], n = 0..63 (+pad)
    __shared__ int bbs[32];

    const int tid = threadIdx.x;
    const int tx = tid & 31;          // col group: n = n0 + tx*2
    const int ty = tid >> 5;          // row group: m = ty*4 (0..7 -> 32 rows)
    const int am = tid >> 3;          // A-load: batch row 0..31
    const int ak = (tid & 7) << 1;    // A-load: k offset 0,2,..,14 (float2)
    const int br = tid >> 2;          // B-load: W row 0..63
    const int bk = (tid & 3) << 2;    // B-load: k offset 0,4,8,12 (float4)

    for (int m0 = s0; m0 < s1; m0 += 32) {
        __syncthreads();  // protect bbs from previous chunk's readers
        if (tid < 32) {
            const int s = m0 + tid;
            bbs[tid] = sorted[s < s1 ? s : s1 - 1];  // dummy-pad with valid idx
        }
        __syncthreads();
        const int cnt = min(32, s1 - m0);

        float acc[4][2] = {};
        for (int k0 = 0; k0 < F; k0 += 16) {
            const float2 av = *reinterpret_cast<const float2*>(
                Ep + (size_t)bbs[am] * F + k0 + ak);
            const float4 bv = *reinterpret_cast<const float4*>(
                Wa + (size_t)(n0 + br) * F + k0 + bk);
            As[ak + 0][am] = av.x; As[ak + 1][am] = av.y;
            Bs[bk + 0][br] = bv.x; Bs[bk + 1][br] = bv.y;
            Bs[bk + 2][br] = bv.z; Bs[bk + 3][br] = bv.w;
            __syncthreads();
            #pragma unroll
            for (int k = 0; k < 16; ++k) {
                const float4 a4 = *reinterpret_cast<const float4*>(&As[k][ty * 4]);
                const float2 b2 = *reinterpret_cast<const float2*>(&Bs[k][tx * 2]);
                acc[0][0] = fmaf(a4.x, b2.x, acc[0][0]); acc[0][1] = fmaf(a4.x, b2.y, acc[0][1]);
                acc[1][0] = fmaf(a4.y, b2.x, acc[1][0]); acc[1][1] = fmaf(a4.y, b2.y, acc[1][1]);
                acc[2][0] = fmaf(a4.z, b2.x, acc[2][0]); acc[2][1] = fmaf(a4.z, b2.y, acc[2][1]);
                acc[3][0] = fmaf(a4.w, b2.x, acc[3][0]); acc[3][1] = fmaf(a4.w, b2.y, acc[3][1]);
            }
            __syncthreads();
        }

        #pragma unroll
        for (int i = 0; i < 4; ++i) {
            const int mm = ty * 4 + i;
            if (mm < cnt) {
                *reinterpret_cast<float2*>(outP + (size_t)bbs[mm] * F + n0 + tx * 2) =
                    make_float2(acc[i][0], acc[i][1]);
            }
        }
    }
}

// ---------------------------------------------------------------------------
extern "C" void kernel_launch(void* const* d_in, const int* in_sizes, int n_in,
                              void* d_out, int out_size, void* d_ws, size_t ws_size,
                              hipStream_t stream) {
    const float* pre    = (const float*)d_in[0];
    const float* eff    = (const float*)d_in[1];
    const int*   action = (const int*)d_in[2];
    const float* W      = (const float*)d_in[3];
    const float* pw     = (const float*)d_in[4];
    const float* pb     = (const float*)d_in[5];
    const float* ew     = (const float*)d_in[6];
    const float* eb     = (const float*)d_in[7];
    const float* gamma  = (const float*)d_in[8];
    const float* beta   = (const float*)d_in[9];

    float* out  = (float*)d_out;
    float* outP = out;                     // [2048,512] p_transformed
    float* outE = out + (size_t)BATCH * F; // [2048,512] e_embed

    // workspace: Np | Ne | Ep | sorted | gstart  (~12.6 MB)
    float* Np = (float*)d_ws;
    float* Ne = Np + (size_t)BATCH * F;
    float* Ep = Ne + (size_t)BATCH * F;
    int* sorted = (int*)(Ep + (size_t)BATCH * F);
    int* gstart = sorted + BATCH;

    k_avg_gn<<<dim3(BATCH, 2), 512, 0, stream>>>(pre, eff, gamma, beta, Np, Ne);
    k_sort<<<1, 256, 0, stream>>>(action, sorted, gstart);
    k_embed<<<dim3(2048 / 64, 512 / 64, 2), 256, 0, stream>>>(Np, Ne, pw, pb, ew, eb, Ep, outE);
    k_transform<<<dim3(NACT, 8), 256, 0, stream>>>(W, Ep, sorted, gstart, outP);
}

// Round 2
// 1085.193 us; speedup vs baseline: 1.0107x; 1.0107x over previous
//
#include <hip/hip_runtime.h>

#define BATCH 2048
#define SEQ 128
#define F 512       // INPUT_DIM == DIM == 512
#define NACT 128
#define GN_EPS 1e-5f

typedef float vfloat4 __attribute__((ext_vector_type(4)));

__device__ __forceinline__ float4 ntload4(const float* p) {
    vfloat4 v = __builtin_nontemporal_load(reinterpret_cast<const vfloat4*>(p));
    return make_float4(v.x, v.y, v.z, v.w);
}

// ---------------------------------------------------------------------------
// Kernel 1: masked mean over SEQ + GroupNorm(1,1) per sample, for both tensors.
// grid (BATCH, 3), block 512:
//   y==0/1 : avg+GN for pre/eff (float4 nontemporal streaming, 1 KB/wave/instr)
//   y==2,x==0 : counting-sort of batches by action (runs CONCURRENTLY with the
//               1 GB stream, hiding its ~15 us entirely; no dependency on it)
// ---------------------------------------------------------------------------
__global__ __launch_bounds__(512) void k_avg_gn(const float* __restrict__ pre,
                                                const float* __restrict__ eff,
                                                const float* __restrict__ gamma,
                                                const float* __restrict__ beta,
                                                const int* __restrict__ action,
                                                float* __restrict__ Np,
                                                float* __restrict__ Ne,
                                                int* __restrict__ sorted,
                                                int* __restrict__ gstart) {
    const int b = blockIdx.x;
    const int t = blockIdx.y;
    const int tid = threadIdx.x;

    __shared__ float psum[4][F];
    __shared__ float pcnt[4][F];
    __shared__ float red[8];
    __shared__ float mv[2];
    __shared__ int cnt[NACT];
    __shared__ int start[NACT + 1];

    if (t == 2) {
        // ---- fused counting sort (single block) ----
        if (b != 0) return;
        if (tid < NACT) cnt[tid] = 0;
        __syncthreads();
        for (int i = tid; i < BATCH; i += 512) atomicAdd(&cnt[action[i]], 1);
        __syncthreads();
        if (tid == 0) {
            int acc = 0;
            for (int a = 0; a < NACT; ++a) { start[a] = acc; acc += cnt[a]; }
            start[NACT] = acc;
        }
        __syncthreads();
        if (tid <= NACT) gstart[tid] = start[tid];
        if (tid < NACT) cnt[tid] = start[tid];  // running offsets
        __syncthreads();
        for (int i = tid; i < BATCH; i += 512) {
            const int pos = atomicAdd(&cnt[action[i]], 1);
            sorted[pos] = i;
        }
        return;
    }

    const float* x = (t == 0 ? pre : eff) + (size_t)b * SEQ * F;
    float* dst = (t == 0 ? Np : Ne) + (size_t)b * F;

    const int g = tid >> 7;           // 0..3 : seq-phase group
    const int fb = (tid & 127) << 2;  // 0..508 : feature base (float4)

    float4 s4 = make_float4(0.f, 0.f, 0.f, 0.f);
    float4 c4 = make_float4(0.f, 0.f, 0.f, 0.f);
    const float* xp = x + (size_t)g * F + fb;
    #pragma unroll 8
    for (int it = 0; it < SEQ / 4; ++it) {
        const float4 v = ntload4(xp + (size_t)it * 4 * F);
        s4.x += v.x; s4.y += v.y; s4.z += v.z; s4.w += v.w;
        c4.x += (v.x != 0.f) ? 1.f : 0.f;
        c4.y += (v.y != 0.f) ? 1.f : 0.f;
        c4.z += (v.z != 0.f) ? 1.f : 0.f;
        c4.w += (v.w != 0.f) ? 1.f : 0.f;
    }
    *reinterpret_cast<float4*>(&psum[g][fb]) = s4;
    *reinterpret_cast<float4*>(&pcnt[g][fb]) = c4;
    __syncthreads();

    const int f = tid;  // 0..511, one feature per thread
    float sum = psum[0][f] + psum[1][f] + psum[2][f] + psum[3][f];
    float cn  = pcnt[0][f] + pcnt[1][f] + pcnt[2][f] + pcnt[3][f];
    const float avg = sum / cn;  // masked mean (cnt==0 -> inf/nan, matches ref)

    const int lane = tid & 63, wv = tid >> 6;

    // mean over the 512 features
    float r = avg;
    #pragma unroll
    for (int off = 32; off; off >>= 1) r += __shfl_down(r, off, 64);
    if (lane == 0) red[wv] = r;
    __syncthreads();
    if (tid == 0) {
        float m = 0.f;
        #pragma unroll
        for (int i = 0; i < 8; ++i) m += red[i];
        mv[0] = m * (1.f / F);
    }
    __syncthreads();
    const float m = mv[0];
    const float d = avg - m;

    // variance (two-pass, matches ref mean((x-m)^2))
    r = d * d;
    #pragma unroll
    for (int off = 32; off; off >>= 1) r += __shfl_down(r, off, 64);
    if (lane == 0) red[wv] = r;
    __syncthreads();
    if (tid == 0) {
        float v = 0.f;
        #pragma unroll
        for (int i = 0; i < 8; ++i) v += red[i];
        mv[1] = v * (1.f / F);
    }
    __syncthreads();
    const float var = mv[1];
    const float inv = 1.f / sqrtf(var + GN_EPS);

    dst[f] = gamma[0] * d * inv + beta[0];
}

// ---------------------------------------------------------------------------
// Kernel 3: embed GEMMs. z=0: Ep = Np @ pw^T + pb (to ws)
//                        z=1: outE = Ne @ ew^T + eb (to d_out second half)
// 64x64 block tile, BK=16, 256 threads, 4x4 micro-tile.
// Reg-staged double buffer: next chunk's global loads issue right after the
// barrier and land during the 256-cycle FMA phase (only 2 blocks/CU here, so
// TLP alone does not hide the load latency).
// ---------------------------------------------------------------------------
__global__ __launch_bounds__(256) void k_embed(const float* __restrict__ Np,
                                               const float* __restrict__ Ne,
                                               const float* __restrict__ pw,
                                               const float* __restrict__ pb,
                                               const float* __restrict__ ew,
                                               const float* __restrict__ eb,
                                               float* __restrict__ Ep,
                                               float* __restrict__ outE) {
    const int z = blockIdx.z;
    const float* A = z ? Ne : Np;     // [2048, 512]
    const float* Bw = z ? ew : pw;    // [512, 512], row i is weight row
    const float* bias = z ? eb : pb;  // [512]
    float* D = z ? outE : Ep;         // [2048, 512]

    const int m0 = blockIdx.x * 64;
    const int n0 = blockIdx.y * 64;

    __shared__ float As[16][68];  // As[k][m]
    __shared__ float Bs[16][68];  // Bs[k][n]

    const int tid = threadIdx.x;
    const int lr = tid >> 2;         // 0..63
    const int lk = (tid & 3) << 2;   // 0,4,8,12
    const int tx = tid & 15, ty = tid >> 4;

    const float* Arow = A + (size_t)(m0 + lr) * F + lk;
    const float* Brow = Bw + (size_t)(n0 + lr) * F + lk;
    const float4 b4 = *reinterpret_cast<const float4*>(bias + n0 + tx * 4);  // hoisted

    float4 av = *reinterpret_cast<const float4*>(Arow);
    float4 bv = *reinterpret_cast<const float4*>(Brow);

    float acc[4][4] = {};
    for (int k0 = 0; k0 < F; k0 += 16) {
        As[lk + 0][lr] = av.x; As[lk + 1][lr] = av.y; As[lk + 2][lr] = av.z; As[lk + 3][lr] = av.w;
        Bs[lk + 0][lr] = bv.x; Bs[lk + 1][lr] = bv.y; Bs[lk + 2][lr] = bv.z; Bs[lk + 3][lr] = bv.w;
        __syncthreads();
        const int kn = (k0 + 16 < F) ? k0 + 16 : 0;  // last-iter load is dummy (cheap, avoids undef)
        float4 av_n = *reinterpret_cast<const float4*>(Arow + kn);
        float4 bv_n = *reinterpret_cast<const float4*>(Brow + kn);
        #pragma unroll
        for (int k = 0; k < 16; ++k) {
            const float4 a = *reinterpret_cast<const float4*>(&As[k][ty * 4]);
            const float4 bq = *reinterpret_cast<const float4*>(&Bs[k][tx * 4]);
            acc[0][0] = fmaf(a.x, bq.x, acc[0][0]); acc[0][1] = fmaf(a.x, bq.y, acc[0][1]);
            acc[0][2] = fmaf(a.x, bq.z, acc[0][2]); acc[0][3] = fmaf(a.x, bq.w, acc[0][3]);
            acc[1][0] = fmaf(a.y, bq.x, acc[1][0]); acc[1][1] = fmaf(a.y, bq.y, acc[1][1]);
            acc[1][2] = fmaf(a.y, bq.z, acc[1][2]); acc[1][3] = fmaf(a.y, bq.w, acc[1][3]);
            acc[2][0] = fmaf(a.z, bq.x, acc[2][0]); acc[2][1] = fmaf(a.z, bq.y, acc[2][1]);
            acc[2][2] = fmaf(a.z, bq.z, acc[2][2]); acc[2][3] = fmaf(a.z, bq.w, acc[2][3]);
            acc[3][0] = fmaf(a.w, bq.x, acc[3][0]); acc[3][1] = fmaf(a.w, bq.y, acc[3][1]);
            acc[3][2] = fmaf(a.w, bq.z, acc[3][2]); acc[3][3] = fmaf(a.w, bq.w, acc[3][3]);
        }
        __syncthreads();
        av = av_n; bv = bv_n;
    }

    #pragma unroll
    for (int i = 0; i < 4; ++i) {
        float4 o;
        o.x = acc[i][0] + b4.x;
        o.y = acc[i][1] + b4.y;
        o.z = acc[i][2] + b4.z;
        o.w = acc[i][3] + b4.w;
        *reinterpret_cast<float4*>(D + (size_t)(m0 + ty * 4 + i) * F + n0 + tx * 4) = o;
    }
}

// ---------------------------------------------------------------------------
// Kernel 4: p_transformed = W[a] @ Ep[b] as per-action tiled GEMM.
// grid (NACT, 8): block = (action a, 64-col tile). 256 threads = 4 waves.
// M-tile 32 (dummy-padded), N-tile 64, BK 16, 4x2 micro-tile.
// Same reg-staged double buffer so the W HBM stream latency hides under FMA.
// ---------------------------------------------------------------------------
__global__ __launch_bounds__(256) void k_transform(const float* __restrict__ W,
                                                   const float* __restrict__ Ep,
                                                   const int* __restrict__ sorted,
                                                   const int* __restrict__ gstart,
                                                   float* __restrict__ outP) {
    const int a = blockIdx.x;
    const int s0 = gstart[a], s1 = gstart[a + 1];
    if (s0 == s1) return;
    const int n0 = blockIdx.y * 64;
    const float* Wa = W + (size_t)a * F * F;

    __shared__ float As[16][36];   // As[k][m], m = 0..31 (+pad)
    __shared__ float Bs[16][68];   // Bs[k][n], n = 0..63 (+pad)
    __shared__ int bbs[32];

    const int tid = threadIdx.x;
    const int tx = tid & 31;          // col group: n = n0 + tx*2
    const int ty = tid >> 5;          // row group: m = ty*4 (0..7 -> 32 rows)
    const int am = tid >> 3;          // A-load: batch row 0..31
    const int ak = (tid & 7) << 1;    // A-load: k offset 0,2,..,14 (float2)
    const int br = tid >> 2;          // B-load: W row 0..63
    const int bk = (tid & 3) << 2;    // B-load: k offset 0,4,8,12 (float4)

    const float* Brow = Wa + (size_t)(n0 + br) * F + bk;

    for (int m0 = s0; m0 < s1; m0 += 32) {
        __syncthreads();  // protect bbs from previous chunk's readers
        if (tid < 32) {
            const int s = m0 + tid;
            bbs[tid] = sorted[s < s1 ? s : s1 - 1];  // dummy-pad with valid idx
        }
        __syncthreads();
        const int cnt = min(32, s1 - m0);
        const float* Arow = Ep + (size_t)bbs[am] * F + ak;

        float2 av = *reinterpret_cast<const float2*>(Arow);
        float4 bv = *reinterpret_cast<const float4*>(Brow);

        float acc[4][2] = {};
        for (int k0 = 0; k0 < F; k0 += 16) {
            As[ak + 0][am] = av.x; As[ak + 1][am] = av.y;
            Bs[bk + 0][br] = bv.x; Bs[bk + 1][br] = bv.y;
            Bs[bk + 2][br] = bv.z; Bs[bk + 3][br] = bv.w;
            __syncthreads();
            const int kn = (k0 + 16 < F) ? k0 + 16 : 0;
            float2 av_n = *reinterpret_cast<const float2*>(Arow + kn);
            float4 bv_n = *reinterpret_cast<const float4*>(Brow + kn);
            #pragma unroll
            for (int k = 0; k < 16; ++k) {
                const float4 a4 = *reinterpret_cast<const float4*>(&As[k][ty * 4]);
                const float2 b2 = *reinterpret_cast<const float2*>(&Bs[k][tx * 2]);
                acc[0][0] = fmaf(a4.x, b2.x, acc[0][0]); acc[0][1] = fmaf(a4.x, b2.y, acc[0][1]);
                acc[1][0] = fmaf(a4.y, b2.x, acc[1][0]); acc[1][1] = fmaf(a4.y, b2.y, acc[1][1]);
                acc[2][0] = fmaf(a4.z, b2.x, acc[2][0]); acc[2][1] = fmaf(a4.z, b2.y, acc[2][1]);
                acc[3][0] = fmaf(a4.w, b2.x, acc[3][0]); acc[3][1] = fmaf(a4.w, b2.y, acc[3][1]);
            }
            __syncthreads();
            av = av_n; bv = bv_n;
        }

        #pragma unroll
        for (int i = 0; i < 4; ++i) {
            const int mm = ty * 4 + i;
            if (mm < cnt) {
                *reinterpret_cast<float2*>(outP + (size_t)bbs[mm] * F + n0 + tx * 2) =
                    make_float2(acc[i][0], acc[i][1]);
            }
        }
    }
}

// ---------------------------------------------------------------------------
extern "C" void kernel_launch(void* const* d_in, const int* in_sizes, int n_in,
                              void* d_out, int out_size, void* d_ws, size_t ws_size,
                              hipStream_t stream) {
    const float* pre    = (const float*)d_in[0];
    const float* eff    = (const float*)d_in[1];
    const int*   action = (const int*)d_in[2];
    const float* W      = (const float*)d_in[3];
    const float* pw     = (const float*)d_in[4];
    const float* pb     = (const float*)d_in[5];
    const float* ew     = (const float*)d_in[6];
    const float* eb     = (const float*)d_in[7];
    const float* gamma  = (const float*)d_in[8];
    const float* beta   = (const float*)d_in[9];

    float* out  = (float*)d_out;
    float* outP = out;                     // [2048,512] p_transformed
    float* outE = out + (size_t)BATCH * F; // [2048,512] e_embed

    // workspace: Np | Ne | Ep | sorted | gstart  (~12.6 MB)
    float* Np = (float*)d_ws;
    float* Ne = Np + (size_t)BATCH * F;
    float* Ep = Ne + (size_t)BATCH * F;
    int* sorted = (int*)(Ep + (size_t)BATCH * F);
    int* gstart = sorted + BATCH;

    k_avg_gn<<<dim3(BATCH, 3), 512, 0, stream>>>(pre, eff, gamma, beta, action,
                                                 Np, Ne, sorted, gstart);
    k_embed<<<dim3(2048 / 64, 512 / 64, 2), 256, 0, stream>>>(Np, Ne, pw, pb, ew, eb, Ep, outE);
    k_transform<<<dim3(NACT, 8), 256, 0, stream>>>(W, Ep, sorted, gstart, outP);
}